// Round 14
// baseline (399.568 us; speedup 1.0000x reference)
//
#include <hip/hip_runtime.h>
#include <hip/hip_bf16.h>

typedef unsigned int u32;
typedef unsigned short u16;
typedef unsigned char u8;

#define NN 50000
#define EE 800000
#define TT 3
#define NBUCK 196        // dst>>8 buckets
#define BSTRIDE 8192     // fixed stride per bucket in TMP (max bucket ~4400)
#define P1_CHUNK 4096

// ws layout (dword offsets) — total 8,953,024 dwords = 35.8 MiB
#define OFF_BCNT   1728      // 256 i (memset-zeroed) — bucket counts
#define OFF_OPART  1984      // 1024 f (memset-zeroed)
#define OFF_ROWPTR 52756     // 50004 i (written by sort_p2)
#define OFF_CW1    102760    // 14336 f: folded layer-0 weights [64 k][224 c]
#define OFF_CW2    117096    // 4352 f: folded layer-1 weights [64 k][68 c]
#define OFF_PSRC   153016    // 800000 i (src | etype<<20, dst-sorted)
#define OFF_PK1    953024    // N*3 rows * 32 dw: [16 dw fp8 F][4 dw bf16 EP][12 pad]
#define OFF_TMP    953024    // overlays PK1 (dead until gemm_f): NBUCK*BSTRIDE
#define OFF_PK2N   5753024   // PK2 in old H region (PK1 stays live during agg1f!):
                             // N*3 rows * 16 dw: [8 dw bf16 F2][EG f32][7 pad]
// memset range: dword 1728 .. 3007 (BCNT+OPART) = 1280 dwords

__device__ __forceinline__ float bf2f(u32 u) {
    union { u32 i; float f; } v; v.i = u << 16; return v.f;
}
__device__ __forceinline__ u32 f2bf(float f) {  // RNE
    union { float f; u32 i; } v; v.f = f;
    return (v.i + 0x7fffu + ((v.i >> 16) & 1u)) >> 16;
}

// Fused precompute + fill_cw: 3 blocks (t), 512 threads. Writes CW1/CW2 directly.
__global__ void weights_k(const float* __restrict__ W1, const float* __restrict__ al1,
                          const float* __restrict__ ar1, const float* __restrict__ W2,
                          const float* __restrict__ al2, const float* __restrict__ ar2,
                          const float* __restrict__ res_w, float* __restrict__ ws) {
    __shared__ float a1c[64][8];
    __shared__ float a2c[16];
    int t = blockIdx.x;
    int tid = threadIdx.x;
    {
        int k2 = tid >> 3, hh = tid & 7;
        float s = 0.f;
#pragma unroll
        for (int j = 0; j < 8; ++j) {
            int idx = t * 4096 + k2 * 64 + hh * 8 + j;
            s += al1[idx] + ar1[idx];
        }
        a1c[k2][hh] = s;
    }
    if (tid < 16) {
        float s = 0.f;
#pragma unroll
        for (int j = 0; j < 16; ++j) {
            int idx = t * 256 + tid * 16 + j;
            s += al2[idx] + ar2[idx];
        }
        a2c[tid] = s;
    }
    __syncthreads();
    for (int q = tid; q < 4096; q += 512) {
        int k = q >> 6, j = q & 63;
        ws[OFF_CW1 + k * 224 + 64 * t + j] = W1[t * 4096 + q];
    }
    {
        int k = tid >> 3, h = tid & 7;
        float s = 0.f;
#pragma unroll
        for (int k2 = 0; k2 < 64; ++k2)
            s += W1[t * 4096 + k * 64 + k2] * a1c[k2][h];
        ws[OFF_CW1 + k * 224 + 192 + 8 * t + h] = s;
    }
    for (int q = tid; q < 1024; q += 512) {
        int k = q >> 4, j = q & 15;
        ws[OFF_CW2 + k * 68 + 16 * t + j] = W2[t * 1024 + q];
    }
    if (tid < 64) {
        float s = 0.f;
#pragma unroll
        for (int k2 = 0; k2 < 16; ++k2)
            s += W2[t * 1024 + tid * 16 + k2] * a2c[k2];
        ws[OFF_CW2 + tid * 68 + 48 + t] = s;
    }
    if (t == 0) {
        for (int q = tid; q < 1024; q += 512) {
            int k = q >> 4, j = q & 15;
            ws[OFF_CW2 + k * 68 + 51 + j] = res_w[q];
        }
        { int k = tid >> 3; ws[OFF_CW1 + k * 224 + 216 + (tid & 7)] = 0.f; }
        if (tid < 64) ws[OFF_CW2 + tid * 68 + 67] = 0.f;
    }
}

// sort pass 1: bucket edges by dst>>8 into fixed-stride TMP regions.
// entry = src[15:0] | etype<<16 [17:16] | (dst&255)<<18 [25:18]
__global__ __launch_bounds__(256) void sort_p1(const int* __restrict__ src, const int* __restrict__ dst,
                        const int* __restrict__ etype, int* wsi) {
    __shared__ u32 Est[P1_CHUNK];
    __shared__ u8 Bst[P1_CHUNK];
    __shared__ int hist[NBUCK], base[NBUCK];
    int tid = threadIdx.x;
    int e0 = blockIdx.x * P1_CHUNK;
    int cnt = EE - e0; if (cnt > P1_CHUNK) cnt = P1_CHUNK;
    for (int i = tid; i < NBUCK; i += 256) hist[i] = 0;
    __syncthreads();
    for (int i = tid; i < cnt; i += 256) {
        int e = e0 + i;
        int s = src[e], d = dst[e], t = etype[e];
        int b = d >> 8;
        Est[i] = (u32)s | ((u32)t << 16) | ((u32)(d & 255) << 18);
        Bst[i] = (u8)b;
        atomicAdd(&hist[b], 1);
    }
    __syncthreads();
    for (int i = tid; i < NBUCK; i += 256) {
        int h = hist[i];
        base[i] = h ? atomicAdd(wsi + OFF_BCNT + i, h) : 0;
        hist[i] = 0;
    }
    __syncthreads();
    for (int i = tid; i < cnt; i += 256) {
        int b = Bst[i];
        int idx = base[b] + atomicAdd(&hist[b], 1);
        wsi[OFF_TMP + b * BSTRIDE + idx] = (int)Est[i];
    }
}

// sort pass 2 (inlined bucket-offset scan): per bucket, count per-dst in LDS,
// scan -> rowptr, scatter into psrc. psrc format: src | etype<<20.
__global__ __launch_bounds__(256) void sort_p2(int* wsi) {
    __shared__ int cnt[256], sd[256], lrpx[256];
    __shared__ int gb_s, nb_s;
    int b = blockIdx.x;
    int tid = threadIdx.x;
    int v0 = (tid < NBUCK) ? wsi[OFF_BCNT + tid] : 0;
    sd[tid] = v0;
    __syncthreads();
    for (int o = 1; o < 256; o <<= 1) {
        int u = (tid >= o) ? sd[tid - o] : 0;
        __syncthreads();
        sd[tid] += u;
        __syncthreads();
    }
    if (tid == 0) {
        int nb = wsi[OFF_BCNT + b];
        gb_s = sd[b] - nb;   // exclusive prefix
        nb_s = nb;
        if (b == 0) wsi[OFF_ROWPTR + NN] = EE;
    }
    __syncthreads();
    int gbase = gb_s, nb = nb_s;
    cnt[tid] = 0;
    __syncthreads();
    const int* tmp = wsi + OFF_TMP + b * BSTRIDE;
    for (int i = tid; i < nb; i += 256) {
        int e = tmp[i];
        atomicAdd(&cnt[(e >> 18) & 255], 1);
    }
    __syncthreads();
    int v = cnt[tid];
    sd[tid] = v;
    __syncthreads();
    for (int o = 1; o < 256; o <<= 1) {
        int u = (tid >= o) ? sd[tid - o] : 0;
        __syncthreads();
        sd[tid] += u;
        __syncthreads();
    }
    int ex = sd[tid] - v;
    lrpx[tid] = ex;
    int d = b * 256 + tid;
    if (d < NN) wsi[OFF_ROWPTR + d] = gbase + ex;
    cnt[tid] = 0;
    __syncthreads();
    for (int i = tid; i < nb; i += 256) {
        int e = tmp[i];
        int dres = (e >> 18) & 255;
        int slot = gbase + lrpx[dres] + atomicAdd(&cnt[dres], 1);
        wsi[OFF_PSRC + slot] = (e & 0xFFFF) | (((e >> 16) & 3) << 20);
    }
}

// PK1[n][t] row (32 dw): F fp8 (dw 0-15) + EP bf16 (dw 16-19).
// r3-exact (53 µs proven).
__global__ __launch_bounds__(512) void gemm_f(const float* __restrict__ x, const float* __restrict__ cw,
                       float* __restrict__ ws) {
    __shared__ alignas(16) float Xs[64 * 65];
    int tid = threadIdx.x;
    int wave = __builtin_amdgcn_readfirstlane(tid >> 6);
    int lane = tid & 63;
    int n0 = blockIdx.x * 64;
    {
        const float4* xg = (const float4*)(x + (size_t)n0 * 64);
        for (int q = tid; q < 1024; q += 512) {
            int row = q >> 4;
            float4 v = (n0 + row < NN) ? xg[q] : make_float4(0.f, 0.f, 0.f, 0.f);
            *(float4*)(Xs + row * 65 + (q & 15) * 4) = v;
        }
    }
    __syncthreads();
    int cbase = wave * 28;
    float acc[28];
#pragma unroll
    for (int i = 0; i < 28; ++i) acc[i] = 0.f;
    const float* xrow = Xs + lane * 65;
    float wA[28], wB[28];
#pragma unroll
    for (int j = 0; j < 28; ++j) wA[j] = cw[cbase + j];
    for (int k = 0; k < 64; k += 2) {
#pragma unroll
        for (int j = 0; j < 28; ++j) wB[j] = cw[(k + 1) * 224 + cbase + j];
        float xv = xrow[k];
#pragma unroll
        for (int j = 0; j < 28; ++j) acc[j] = fmaf(xv, wA[j], acc[j]);
        if (k + 2 < 64) {
#pragma unroll
            for (int j = 0; j < 28; ++j) wA[j] = cw[(k + 2) * 224 + cbase + j];
        }
        float xv2 = xrow[k + 1];
#pragma unroll
        for (int j = 0; j < 28; ++j) acc[j] = fmaf(xv2, wB[j], acc[j]);
    }
    int n = n0 + lane;
    if (n < NN) {
        u32* row = (u32*)ws + OFF_PK1 + (size_t)n * 96;
#pragma unroll
        for (int g = 0; g < 7; ++g) {
            int col = cbase + 4 * g;
            float v0 = acc[4*g], v1 = acc[4*g+1], v2 = acc[4*g+2], v3 = acc[4*g+3];
            if (col < 192) {
                int t = col >> 6, ci = col & 63;
                int dw = __builtin_amdgcn_cvt_pk_fp8_f32(v0, v1, 0, false);
                dw = __builtin_amdgcn_cvt_pk_fp8_f32(v2, v3, dw, true);
                row[t * 32 + (ci >> 2)] = (u32)dw;
            } else if (col < 216) {
                int jj = col - 192;
                int t = jj >> 3, rem = jj & 7;  // rem in {0,4}
                v0 = v0 > 0.f ? v0 : 0.2f * v0;
                v1 = v1 > 0.f ? v1 : 0.2f * v1;
                v2 = v2 > 0.f ? v2 : 0.2f * v2;
                v3 = v3 > 0.f ? v3 : 0.2f * v3;
                row[t * 32 + 16 + (rem >> 1)]     = f2bf(__expf(v0)) | (f2bf(__expf(v1)) << 16);
                row[t * 32 + 16 + (rem >> 1) + 1] = f2bf(__expf(v2)) | (f2bf(__expf(v3)) << 16);
            }
        }
    }
}

// layer0 softmax+aggregate FUSED with layer1 typed-linear (was gemm_f2).
// 4 waves/block, wave = node; 8-way edge-parallel gather. After the
// xor-reduce every lane holds acc[0..7] = h[8*(lane&7)+i] — F2 = h·CW2 done
// in-register: lane = column, h[k] via __shfl broadcast in ascending-k order
// (matches gemm_f2's accumulation order), CW2 L1-hot (17 KB).
// Residual epilogue: race-free Rs[4][16] per-wave slots (NO LDS atomics —
// r12/r13 container failures' only untested construct was ds_add_f32; this
// uses the measured gemm_f2-style pattern instead).
__global__ __launch_bounds__(256) void agg1f(const int* __restrict__ wsi, const float* __restrict__ cw2,
                                             float* __restrict__ ws) {
    __shared__ float Rs[4][16];
    int tid = threadIdx.x;
    int wave = tid >> 6, lane = tid & 63;
    int q = lane >> 3;
    int cg = lane & 7;
    int d = blockIdx.x * 4 + wave;
    int epw = cg >> 1;
    int sh_ep = (cg & 1) * 16;
    int start = wsi[OFF_ROWPTR + d], end = wsi[OFF_ROWPTR + d + 1];
    const u32* pk = (const u32*)ws + OFF_PK1;
    const int* psrc = wsi + OFF_PSRC;
    float acc[8];
#pragma unroll
    for (int i = 0; i < 8; ++i) acc[i] = 0.f;
    float den = 0.f;
    int s = start + q;
    u32 f0_c = 0, f1_c = 0, ep_c = 0;
    int p1 = 0;
    bool valid = s < end;
    if (valid) {
        int p = psrc[s];
        int sn = p & 0xFFFFF, t = p >> 20;
        size_t base = (size_t)(sn * 3 + t) * 32;
        uint2 f = *(const uint2*)(pk + base + 2 * cg);
        f0_c = f.x; f1_c = f.y;
        ep_c = pk[base + 16 + epw];
    }
    if (s + 8 < end) p1 = psrc[s + 8];
    while (valid) {
        u32 f0 = f0_c, f1 = f1_c, ep = ep_c;
        bool v1 = s + 8 < end;
        if (v1) {
            int sn = p1 & 0xFFFFF, t = p1 >> 20;
            size_t base = (size_t)(sn * 3 + t) * 32;
            uint2 f = *(const uint2*)(pk + base + 2 * cg);
            f0_c = f.x; f1_c = f.y;
            ep_c = pk[base + 16 + epw];
        }
        if (s + 16 < end) p1 = psrc[s + 16];
        float w = bf2f((ep >> sh_ep) & 0xffffu);
        den += w;
        acc[0] += w * __builtin_amdgcn_cvt_f32_fp8((int)f0, 0);
        acc[1] += w * __builtin_amdgcn_cvt_f32_fp8((int)(f0 >> 8), 0);
        acc[2] += w * __builtin_amdgcn_cvt_f32_fp8((int)(f0 >> 16), 0);
        acc[3] += w * __builtin_amdgcn_cvt_f32_fp8((int)(f0 >> 24), 0);
        acc[4] += w * __builtin_amdgcn_cvt_f32_fp8((int)f1, 0);
        acc[5] += w * __builtin_amdgcn_cvt_f32_fp8((int)(f1 >> 8), 0);
        acc[6] += w * __builtin_amdgcn_cvt_f32_fp8((int)(f1 >> 16), 0);
        acc[7] += w * __builtin_amdgcn_cvt_f32_fp8((int)(f1 >> 24), 0);
        s += 8;
        valid = v1;
    }
#pragma unroll
    for (int i = 0; i < 8; ++i) {
        acc[i] += __shfl_xor(acc[i], 8);
        acc[i] += __shfl_xor(acc[i], 16);
        acc[i] += __shfl_xor(acc[i], 32);
    }
    den += __shfl_xor(den, 8);
    den += __shfl_xor(den, 16);
    den += __shfl_xor(den, 32);
    // every lane: h slice for k = (lane&7)*8 + i
    float dn = (end > start) ? den : 1.f;
    float h[8];
#pragma unroll
    for (int i = 0; i < 8; ++i) {
        float v = acc[i] / dn;
        h[i] = v > 0.f ? v : __expf(v) - 1.f;  // ELU
    }
    // fused layer-1: lane c computes F2/EG/res col c; lanes 0-2 also col 64+c
    float a2 = 0.f, a2b = 0.f;
    bool extra = lane < 3;
#pragma unroll
    for (int g = 0; g < 8; ++g) {
        float hg[8];
#pragma unroll
        for (int i = 0; i < 8; ++i) hg[i] = __shfl(h[i], g);
#pragma unroll
        for (int i = 0; i < 8; ++i) {
            int k = g * 8 + i;
            a2 = fmaf(hg[i], cw2[k * 68 + lane], a2);
            if (extra) a2b = fmaf(hg[i], cw2[k * 68 + 64 + lane], a2b);
        }
    }
    u16* pk2u = (u16*)((u32*)ws + OFF_PK2N);
    float* pk2f = ws + OFF_PK2N;
    int c = lane;
    if (c < 48) {
        pk2u[((size_t)d * 3 + (c >> 4)) * 32 + (c & 15)] = (u16)f2bf(a2);
    } else if (c < 51) {
        float v = a2 > 0.f ? a2 : 0.2f * a2;
        pk2f[((size_t)d * 3 + (c - 48)) * 16 + 8] = __expf(v);
    } else {
        Rs[wave][c - 51] = a2;              // res cols 0..12 (lanes 51..63)
    }
    if (extra) Rs[wave][13 + lane] = a2b;   // res cols 13..15 (lanes 0..2)
    __syncthreads();
    if (tid < 16) {
        float sum = Rs[0][tid] + Rs[1][tid] + Rs[2][tid] + Rs[3][tid];
        atomicAdd(ws + OFF_OPART + (blockIdx.x & 63) * 16 + tid, sum);
    }
}

// layer1 fused aggregate — PK2N single-line gathers. (r10 lesson: NO per-block
// __threadfence last-block fusion — keep the separate 1-block final_k.)
__global__ __launch_bounds__(256) void agg2(const int* __restrict__ wsi, float* __restrict__ ws) {
    __shared__ float outs[4][16];
    int tid = threadIdx.x;
    int wave = tid >> 6, lane = tid & 63;
    int q = lane >> 4, c = lane & 15;
    int d = blockIdx.x * 4 + wave;
    int start = wsi[OFF_ROWPTR + d], end = wsi[OFF_ROWPTR + d + 1];
    const u16* pk2u = (const u16*)((const u32*)ws + OFF_PK2N);
    const float* pk2f = ws + OFF_PK2N;
    const int* psrc = wsi + OFF_PSRC;
    float acc = 0.f, den = 0.f;
    int s = start + q;
    float w_c = 0.f, m_c = 0.f;
    bool valid = s < end;
    if (valid) {
        int p = psrc[s];
        int sn = p & 0xFFFFF, t = p >> 20;
        size_t r = (size_t)(sn * 3 + t);
        w_c = pk2f[r * 16 + 8];
        m_c = bf2f(pk2u[r * 32 + c]);
    }
    while (valid) {
        float w = w_c, m = m_c;
        int s2 = s + 4;
        bool v2 = s2 < end;
        if (v2) {
            int p = psrc[s2];
            int sn = p & 0xFFFFF, t = p >> 20;
            size_t r = (size_t)(sn * 3 + t);
            w_c = pk2f[r * 16 + 8];
            m_c = bf2f(pk2u[r * 32 + c]);
        }
        den += w;
        acc += w * m;
        s = s2; valid = v2;
    }
    acc += __shfl_xor(acc, 16);
    acc += __shfl_xor(acc, 32);
    den += __shfl_xor(den, 16);
    den += __shfl_xor(den, 32);
    float val = (end > start) ? acc / den : 0.f;
    if (q == 0) outs[wave][c] = val;
    __syncthreads();
    if (tid < 16) {
        float sum = outs[0][tid] + outs[1][tid] + outs[2][tid] + outs[3][tid];
        atomicAdd(ws + OFF_OPART + (blockIdx.x & 63) * 16 + tid, sum);
    }
}

__global__ void final_k(const float* __restrict__ res_b, float* __restrict__ ws, float* __restrict__ out) {
    int c = threadIdx.x;
    if (c < 16) {
        float s = 0.f;
        for (int r = 0; r < 64; ++r) s += ws[OFF_OPART + r * 16 + c];
        out[c] = s * (1.0f / (float)NN) + res_b[c];
    }
}

extern "C" void kernel_launch(void* const* d_in, const int* in_sizes, int n_in,
                              void* d_out, int out_size, void* d_ws, size_t ws_size,
                              hipStream_t stream) {
    const float* x     = (const float*)d_in[0];
    const int*   src   = (const int*)d_in[1];
    const int*   dst   = (const int*)d_in[2];
    // d_in[3] = ntype (unused by reference)
    const int*   etype = (const int*)d_in[4];
    const float* W1    = (const float*)d_in[5];
    const float* al1   = (const float*)d_in[6];
    const float* ar1   = (const float*)d_in[7];
    const float* W2    = (const float*)d_in[8];
    const float* al2   = (const float*)d_in[9];
    const float* ar2   = (const float*)d_in[10];
    const float* res_w = (const float*)d_in[11];
    const float* res_b = (const float*)d_in[12];
    float* ws = (float*)d_ws;
    int* wsi = (int*)d_ws;
    float* out = (float*)d_out;

    hipMemsetAsync((char*)d_ws + (size_t)OFF_BCNT * 4, 0, (size_t)1280 * 4, stream);
    hipLaunchKernelGGL(weights_k, dim3(TT), dim3(512), 0, stream, W1, al1, ar1, W2, al2, ar2, res_w, ws);
    hipLaunchKernelGGL(sort_p1, dim3((EE + P1_CHUNK - 1) / P1_CHUNK), dim3(256), 0, stream, src, dst, etype, wsi);
    hipLaunchKernelGGL(sort_p2, dim3(NBUCK), dim3(256), 0, stream, wsi);
    hipLaunchKernelGGL(gemm_f, dim3((NN + 63) / 64), dim3(512), 0, stream, x, ws + OFF_CW1, ws);
    hipLaunchKernelGGL(agg1f, dim3(NN / 4), dim3(256), 0, stream, wsi, ws + OFF_CW2, ws);
    hipLaunchKernelGGL(agg2, dim3(NN / 4), dim3(256), 0, stream, wsi, ws);
    hipLaunchKernelGGL(final_k, dim3(1), dim3(64), 0, stream, res_b, ws, out);
}

// Round 15
// 256.036 us; speedup vs baseline: 1.5606x; 1.5606x over previous
//
#include <hip/hip_runtime.h>
#include <hip/hip_bf16.h>

typedef unsigned int u32;
typedef unsigned short u16;
typedef unsigned char u8;

#define NN 50000
#define EE 800000
#define TT 3
#define NBUCK 196        // dst>>8 buckets
#define BSTRIDE 8192     // fixed stride per bucket in TMP (max bucket ~4400)
#define P1_CHUNK 4096

// ws layout (dword offsets) — total 8,953,024 dwords = 35.8 MiB
#define OFF_BCNT   1728      // 256 i (memset-zeroed) — bucket counts
#define OFF_OPART  1984      // 1024 f (memset-zeroed)
#define OFF_ROWPTR 52756     // 50004 i (written by sort_p2)
#define OFF_CW1    102760    // 14336 f: folded layer-0 weights [64 k][224 c]
#define OFF_CW2    117096    // 4352 f: folded layer-1 weights [64 k][68 c]
#define OFF_PSRC   153016    // 800000 i (src | etype<<20, dst-sorted)
#define OFF_PK1    953024    // N*3 rows * 32 dw: [16 dw fp8 F][4 dw bf16 EP][12 pad]
#define OFF_TMP    953024    // overlays PK1 (dead until gemm_f): NBUCK*BSTRIDE
#define OFF_PK2    953024    // overlays PK1 (dead after agg1): N*3 rows * 16 dw
#define OFF_H      5753024   // N*64 f = 3,200,000
// memset range: dword 1728 .. 3007 (BCNT+OPART) = 1280 dwords

__device__ __forceinline__ float bf2f(u32 u) {
    union { u32 i; float f; } v; v.i = u << 16; return v.f;
}
__device__ __forceinline__ u32 f2bf(float f) {  // RNE
    union { float f; u32 i; } v; v.f = f;
    return (v.i + 0x7fffu + ((v.i >> 16) & 1u)) >> 16;
}

// Fused precompute + fill_cw (r14-verified): 3 blocks (t), 512 threads.
__global__ void weights_k(const float* __restrict__ W1, const float* __restrict__ al1,
                          const float* __restrict__ ar1, const float* __restrict__ W2,
                          const float* __restrict__ al2, const float* __restrict__ ar2,
                          const float* __restrict__ res_w, float* __restrict__ ws) {
    __shared__ float a1c[64][8];
    __shared__ float a2c[16];
    int t = blockIdx.x;
    int tid = threadIdx.x;
    {
        int k2 = tid >> 3, hh = tid & 7;
        float s = 0.f;
#pragma unroll
        for (int j = 0; j < 8; ++j) {
            int idx = t * 4096 + k2 * 64 + hh * 8 + j;
            s += al1[idx] + ar1[idx];
        }
        a1c[k2][hh] = s;
    }
    if (tid < 16) {
        float s = 0.f;
#pragma unroll
        for (int j = 0; j < 16; ++j) {
            int idx = t * 256 + tid * 16 + j;
            s += al2[idx] + ar2[idx];
        }
        a2c[tid] = s;
    }
    __syncthreads();
    for (int q = tid; q < 4096; q += 512) {
        int k = q >> 6, j = q & 63;
        ws[OFF_CW1 + k * 224 + 64 * t + j] = W1[t * 4096 + q];
    }
    {
        int k = tid >> 3, h = tid & 7;
        float s = 0.f;
#pragma unroll
        for (int k2 = 0; k2 < 64; ++k2)
            s += W1[t * 4096 + k * 64 + k2] * a1c[k2][h];
        ws[OFF_CW1 + k * 224 + 192 + 8 * t + h] = s;
    }
    for (int q = tid; q < 1024; q += 512) {
        int k = q >> 4, j = q & 15;
        ws[OFF_CW2 + k * 68 + 16 * t + j] = W2[t * 1024 + q];
    }
    if (tid < 64) {
        float s = 0.f;
#pragma unroll
        for (int k2 = 0; k2 < 16; ++k2)
            s += W2[t * 1024 + tid * 16 + k2] * a2c[k2];
        ws[OFF_CW2 + tid * 68 + 48 + t] = s;
    }
    if (t == 0) {
        for (int q = tid; q < 1024; q += 512) {
            int k = q >> 4, j = q & 15;
            ws[OFF_CW2 + k * 68 + 51 + j] = res_w[q];
        }
        { int k = tid >> 3; ws[OFF_CW1 + k * 224 + 216 + (tid & 7)] = 0.f; }
        if (tid < 64) ws[OFF_CW2 + tid * 68 + 67] = 0.f;
    }
}

// sort pass 1 (r14-verified): bucket edges by dst>>8 into fixed-stride TMP.
// entry = src[15:0] | etype<<16 [17:16] | (dst&255)<<18 [25:18]
__global__ __launch_bounds__(256) void sort_p1(const int* __restrict__ src, const int* __restrict__ dst,
                        const int* __restrict__ etype, int* wsi) {
    __shared__ u32 Est[P1_CHUNK];
    __shared__ u8 Bst[P1_CHUNK];
    __shared__ int hist[NBUCK], base[NBUCK];
    int tid = threadIdx.x;
    int e0 = blockIdx.x * P1_CHUNK;
    int cnt = EE - e0; if (cnt > P1_CHUNK) cnt = P1_CHUNK;
    for (int i = tid; i < NBUCK; i += 256) hist[i] = 0;
    __syncthreads();
    for (int i = tid; i < cnt; i += 256) {
        int e = e0 + i;
        int s = src[e], d = dst[e], t = etype[e];
        int b = d >> 8;
        Est[i] = (u32)s | ((u32)t << 16) | ((u32)(d & 255) << 18);
        Bst[i] = (u8)b;
        atomicAdd(&hist[b], 1);
    }
    __syncthreads();
    for (int i = tid; i < NBUCK; i += 256) {
        int h = hist[i];
        base[i] = h ? atomicAdd(wsi + OFF_BCNT + i, h) : 0;
        hist[i] = 0;
    }
    __syncthreads();
    for (int i = tid; i < cnt; i += 256) {
        int b = Bst[i];
        int idx = base[b] + atomicAdd(&hist[b], 1);
        wsi[OFF_TMP + b * BSTRIDE + idx] = (int)Est[i];
    }
}

// sort pass 2 (r14-verified, inline bucket-offset scan): count per-dst in LDS,
// scan -> rowptr, scatter into psrc. psrc format: src | etype<<20.
__global__ __launch_bounds__(256) void sort_p2(int* wsi) {
    __shared__ int cnt[256], sd[256], lrpx[256];
    __shared__ int gb_s, nb_s;
    int b = blockIdx.x;
    int tid = threadIdx.x;
    int v0 = (tid < NBUCK) ? wsi[OFF_BCNT + tid] : 0;
    sd[tid] = v0;
    __syncthreads();
    for (int o = 1; o < 256; o <<= 1) {
        int u = (tid >= o) ? sd[tid - o] : 0;
        __syncthreads();
        sd[tid] += u;
        __syncthreads();
    }
    if (tid == 0) {
        int nb = wsi[OFF_BCNT + b];
        gb_s = sd[b] - nb;   // exclusive prefix
        nb_s = nb;
        if (b == 0) wsi[OFF_ROWPTR + NN] = EE;
    }
    __syncthreads();
    int gbase = gb_s, nb = nb_s;
    cnt[tid] = 0;
    __syncthreads();
    const int* tmp = wsi + OFF_TMP + b * BSTRIDE;
    for (int i = tid; i < nb; i += 256) {
        int e = tmp[i];
        atomicAdd(&cnt[(e >> 18) & 255], 1);
    }
    __syncthreads();
    int v = cnt[tid];
    sd[tid] = v;
    __syncthreads();
    for (int o = 1; o < 256; o <<= 1) {
        int u = (tid >= o) ? sd[tid - o] : 0;
        __syncthreads();
        sd[tid] += u;
        __syncthreads();
    }
    int ex = sd[tid] - v;
    lrpx[tid] = ex;
    int d = b * 256 + tid;
    if (d < NN) wsi[OFF_ROWPTR + d] = gbase + ex;
    cnt[tid] = 0;
    __syncthreads();
    for (int i = tid; i < nb; i += 256) {
        int e = tmp[i];
        int dres = (e >> 18) & 255;
        int slot = gbase + lrpx[dres] + atomicAdd(&cnt[dres], 1);
        wsi[OFF_PSRC + slot] = (e & 0xFFFF) | (((e >> 16) & 3) << 20);
    }
}

// PK1[n][t] row (32 dw): F fp8 (dw 0-15) + EP bf16 (dw 16-19).
// r3-exact (53 µs proven across r3/r8/r14).
__global__ __launch_bounds__(512) void gemm_f(const float* __restrict__ x, const float* __restrict__ cw,
                       float* __restrict__ ws) {
    __shared__ alignas(16) float Xs[64 * 65];
    int tid = threadIdx.x;
    int wave = __builtin_amdgcn_readfirstlane(tid >> 6);
    int lane = tid & 63;
    int n0 = blockIdx.x * 64;
    {
        const float4* xg = (const float4*)(x + (size_t)n0 * 64);
        for (int q = tid; q < 1024; q += 512) {
            int row = q >> 4;
            float4 v = (n0 + row < NN) ? xg[q] : make_float4(0.f, 0.f, 0.f, 0.f);
            *(float4*)(Xs + row * 65 + (q & 15) * 4) = v;
        }
    }
    __syncthreads();
    int cbase = wave * 28;
    float acc[28];
#pragma unroll
    for (int i = 0; i < 28; ++i) acc[i] = 0.f;
    const float* xrow = Xs + lane * 65;
    float wA[28], wB[28];
#pragma unroll
    for (int j = 0; j < 28; ++j) wA[j] = cw[cbase + j];
    for (int k = 0; k < 64; k += 2) {
#pragma unroll
        for (int j = 0; j < 28; ++j) wB[j] = cw[(k + 1) * 224 + cbase + j];
        float xv = xrow[k];
#pragma unroll
        for (int j = 0; j < 28; ++j) acc[j] = fmaf(xv, wA[j], acc[j]);
        if (k + 2 < 64) {
#pragma unroll
            for (int j = 0; j < 28; ++j) wA[j] = cw[(k + 2) * 224 + cbase + j];
        }
        float xv2 = xrow[k + 1];
#pragma unroll
        for (int j = 0; j < 28; ++j) acc[j] = fmaf(xv2, wB[j], acc[j]);
    }
    int n = n0 + lane;
    if (n < NN) {
        u32* row = (u32*)ws + OFF_PK1 + (size_t)n * 96;
#pragma unroll
        for (int g = 0; g < 7; ++g) {
            int col = cbase + 4 * g;
            float v0 = acc[4*g], v1 = acc[4*g+1], v2 = acc[4*g+2], v3 = acc[4*g+3];
            if (col < 192) {
                int t = col >> 6, ci = col & 63;
                int dw = __builtin_amdgcn_cvt_pk_fp8_f32(v0, v1, 0, false);
                dw = __builtin_amdgcn_cvt_pk_fp8_f32(v2, v3, dw, true);
                row[t * 32 + (ci >> 2)] = (u32)dw;
            } else if (col < 216) {
                int jj = col - 192;
                int t = jj >> 3, rem = jj & 7;  // rem in {0,4}
                v0 = v0 > 0.f ? v0 : 0.2f * v0;
                v1 = v1 > 0.f ? v1 : 0.2f * v1;
                v2 = v2 > 0.f ? v2 : 0.2f * v2;
                v3 = v3 > 0.f ? v3 : 0.2f * v3;
                row[t * 32 + 16 + (rem >> 1)]     = f2bf(__expf(v0)) | (f2bf(__expf(v1)) << 16);
                row[t * 32 + 16 + (rem >> 1) + 1] = f2bf(__expf(v2)) | (f2bf(__expf(v3)) << 16);
            }
        }
    }
}

// layer0 fused softmax+aggregate — 8-way edge-parallel per wave (r8-measured).
// SPLIT from layer-1 on purpose: r14's fusion raised VGPR 12->72 and halved
// occupancy on this latency-bound gather (209 µs vs ~52 for the split pair).
__global__ __launch_bounds__(256) void agg1(const int* __restrict__ wsi, float* __restrict__ ws) {
    int tid = threadIdx.x;
    int wave = tid >> 6, lane = tid & 63;
    int q = lane >> 3;
    int cg = lane & 7;
    int d = blockIdx.x * 4 + wave;
    int epw = cg >> 1;
    int sh_ep = (cg & 1) * 16;
    int start = wsi[OFF_ROWPTR + d], end = wsi[OFF_ROWPTR + d + 1];
    const u32* pk = (const u32*)ws + OFF_PK1;
    const int* psrc = wsi + OFF_PSRC;
    float acc[8];
#pragma unroll
    for (int i = 0; i < 8; ++i) acc[i] = 0.f;
    float den = 0.f;
    int s = start + q;
    u32 f0_c = 0, f1_c = 0, ep_c = 0;
    int p1 = 0;
    bool valid = s < end;
    if (valid) {
        int p = psrc[s];
        int sn = p & 0xFFFFF, t = p >> 20;
        size_t base = (size_t)(sn * 3 + t) * 32;
        uint2 f = *(const uint2*)(pk + base + 2 * cg);
        f0_c = f.x; f1_c = f.y;
        ep_c = pk[base + 16 + epw];
    }
    if (s + 8 < end) p1 = psrc[s + 8];
    while (valid) {
        u32 f0 = f0_c, f1 = f1_c, ep = ep_c;
        bool v1 = s + 8 < end;
        if (v1) {
            int sn = p1 & 0xFFFFF, t = p1 >> 20;
            size_t base = (size_t)(sn * 3 + t) * 32;
            uint2 f = *(const uint2*)(pk + base + 2 * cg);
            f0_c = f.x; f1_c = f.y;
            ep_c = pk[base + 16 + epw];
        }
        if (s + 16 < end) p1 = psrc[s + 16];
        float w = bf2f((ep >> sh_ep) & 0xffffu);
        den += w;
        acc[0] += w * __builtin_amdgcn_cvt_f32_fp8((int)f0, 0);
        acc[1] += w * __builtin_amdgcn_cvt_f32_fp8((int)(f0 >> 8), 0);
        acc[2] += w * __builtin_amdgcn_cvt_f32_fp8((int)(f0 >> 16), 0);
        acc[3] += w * __builtin_amdgcn_cvt_f32_fp8((int)(f0 >> 24), 0);
        acc[4] += w * __builtin_amdgcn_cvt_f32_fp8((int)f1, 0);
        acc[5] += w * __builtin_amdgcn_cvt_f32_fp8((int)(f1 >> 8), 0);
        acc[6] += w * __builtin_amdgcn_cvt_f32_fp8((int)(f1 >> 16), 0);
        acc[7] += w * __builtin_amdgcn_cvt_f32_fp8((int)(f1 >> 24), 0);
        s += 8;
        valid = v1;
    }
#pragma unroll
    for (int i = 0; i < 8; ++i) {
        acc[i] += __shfl_xor(acc[i], 8);
        acc[i] += __shfl_xor(acc[i], 16);
        acc[i] += __shfl_xor(acc[i], 32);
    }
    den += __shfl_xor(den, 8);
    den += __shfl_xor(den, 16);
    den += __shfl_xor(den, 32);
    if (q == 0) {
        float dn = (end > start) ? den : 1.f;
        float o[8];
#pragma unroll
        for (int i = 0; i < 8; ++i) {
            float v = acc[i] / dn;
            o[i] = v > 0.f ? v : __expf(v) - 1.f;  // ELU
        }
        float* dst = ws + OFF_H + (size_t)d * 64 + cg * 8;
        *(float4*)dst       = make_float4(o[0], o[1], o[2], o[3]);
        *(float4*)(dst + 4) = make_float4(o[4], o[5], o[6], o[7]);
    }
}

// PK2[n][t] = [16 bf16 F2][EG f32]; residual partials to OPART.
// r3-exact (measured r8): 4 waves; wave = 17-col slice, lane = node.
__global__ __launch_bounds__(256) void gemm_f2(const float* __restrict__ cw, float* __restrict__ ws) {
    __shared__ alignas(16) float Hs[64 * 65];
    __shared__ float Rs[64][17];
    int tid = threadIdx.x;
    int wave = __builtin_amdgcn_readfirstlane(tid >> 6);
    int lane = tid & 63;
    int n0 = blockIdx.x * 64;
    {
        const float4* hg = (const float4*)(ws + OFF_H + (size_t)n0 * 64);
        for (int q = tid; q < 1024; q += 256) {
            int row = q >> 4;
            float4 v = (n0 + row < NN) ? hg[q] : make_float4(0.f, 0.f, 0.f, 0.f);
            *(float4*)(Hs + row * 65 + (q & 15) * 4) = v;
        }
    }
    __syncthreads();
    int cbase = wave * 17;
    float acc[17];
#pragma unroll
    for (int i = 0; i < 17; ++i) acc[i] = 0.f;
    const float* hrow = Hs + lane * 65;
    float wA[17], wB[17];
#pragma unroll
    for (int j = 0; j < 17; ++j) wA[j] = cw[cbase + j];
    for (int k = 0; k < 64; k += 2) {
#pragma unroll
        for (int j = 0; j < 17; ++j) wB[j] = cw[(k + 1) * 68 + cbase + j];
        float hv = hrow[k];
#pragma unroll
        for (int j = 0; j < 17; ++j) acc[j] = fmaf(hv, wA[j], acc[j]);
        if (k + 2 < 64) {
#pragma unroll
            for (int j = 0; j < 17; ++j) wA[j] = cw[(k + 2) * 68 + cbase + j];
        }
        float hv2 = hrow[k + 1];
#pragma unroll
        for (int j = 0; j < 17; ++j) acc[j] = fmaf(hv2, wB[j], acc[j]);
    }
    int n = n0 + lane;
    u16* pk2u = (u16*)((u32*)ws + OFF_PK2);
#pragma unroll
    for (int i = 0; i < 17; ++i) {
        int col = cbase + i;
        if (col < 48) {
            if (n < NN) {
                int t = col >> 4, c2 = col & 15;
                pk2u[((size_t)n * 3 + t) * 32 + c2] = (u16)f2bf(acc[i]);
            }
        } else if (col < 51) {
            if (n < NN) {
                float v = acc[i]; v = v > 0.f ? v : 0.2f * v;
                ws[OFF_PK2 + ((size_t)n * 3 + (col - 48)) * 16 + 8] = __expf(v);
            }
        } else if (col < 67) {
            Rs[lane][col - 51] = acc[i];
        }
    }
    __syncthreads();
    if (tid < 16) {
        float s = 0.f;
#pragma unroll 8
        for (int r = 0; r < 64; ++r) s += Rs[r][tid];
        atomicAdd(ws + OFF_OPART + (blockIdx.x & 63) * 16 + tid, s);
    }
}

// layer1 fused aggregate — PK2 single-line gathers (r8-measured).
__global__ __launch_bounds__(256) void agg2(const int* __restrict__ wsi, float* __restrict__ ws) {
    __shared__ float outs[4][16];
    int tid = threadIdx.x;
    int wave = tid >> 6, lane = tid & 63;
    int q = lane >> 4, c = lane & 15;
    int d = blockIdx.x * 4 + wave;
    int start = wsi[OFF_ROWPTR + d], end = wsi[OFF_ROWPTR + d + 1];
    const u16* pk2u = (const u16*)((const u32*)ws + OFF_PK2);
    const float* pk2f = ws + OFF_PK2;
    const int* psrc = wsi + OFF_PSRC;
    float acc = 0.f, den = 0.f;
    int s = start + q;
    float w_c = 0.f, m_c = 0.f;
    bool valid = s < end;
    if (valid) {
        int p = psrc[s];
        int sn = p & 0xFFFFF, t = p >> 20;
        size_t r = (size_t)(sn * 3 + t);
        w_c = pk2f[r * 16 + 8];
        m_c = bf2f(pk2u[r * 32 + c]);
    }
    while (valid) {
        float w = w_c, m = m_c;
        int s2 = s + 4;
        bool v2 = s2 < end;
        if (v2) {
            int p = psrc[s2];
            int sn = p & 0xFFFFF, t = p >> 20;
            size_t r = (size_t)(sn * 3 + t);
            w_c = pk2f[r * 16 + 8];
            m_c = bf2f(pk2u[r * 32 + c]);
        }
        den += w;
        acc += w * m;
        s = s2; valid = v2;
    }
    acc += __shfl_xor(acc, 16);
    acc += __shfl_xor(acc, 32);
    den += __shfl_xor(den, 16);
    den += __shfl_xor(den, 32);
    float val = (end > start) ? acc / den : 0.f;
    if (q == 0) outs[wave][c] = val;
    __syncthreads();
    if (tid < 16) {
        float sum = outs[0][tid] + outs[1][tid] + outs[2][tid] + outs[3][tid];
        atomicAdd(ws + OFF_OPART + (blockIdx.x & 63) * 16 + tid, sum);
    }
}

__global__ void final_k(const float* __restrict__ res_b, float* __restrict__ ws, float* __restrict__ out) {
    int c = threadIdx.x;
    if (c < 16) {
        float s = 0.f;
        for (int r = 0; r < 64; ++r) s += ws[OFF_OPART + r * 16 + c];
        out[c] = s * (1.0f / (float)NN) + res_b[c];
    }
}

extern "C" void kernel_launch(void* const* d_in, const int* in_sizes, int n_in,
                              void* d_out, int out_size, void* d_ws, size_t ws_size,
                              hipStream_t stream) {
    const float* x     = (const float*)d_in[0];
    const int*   src   = (const int*)d_in[1];
    const int*   dst   = (const int*)d_in[2];
    // d_in[3] = ntype (unused by reference)
    const int*   etype = (const int*)d_in[4];
    const float* W1    = (const float*)d_in[5];
    const float* al1   = (const float*)d_in[6];
    const float* ar1   = (const float*)d_in[7];
    const float* W2    = (const float*)d_in[8];
    const float* al2   = (const float*)d_in[9];
    const float* ar2   = (const float*)d_in[10];
    const float* res_w = (const float*)d_in[11];
    const float* res_b = (const float*)d_in[12];
    float* ws = (float*)d_ws;
    int* wsi = (int*)d_ws;
    float* out = (float*)d_out;

    hipMemsetAsync((char*)d_ws + (size_t)OFF_BCNT * 4, 0, (size_t)1280 * 4, stream);
    hipLaunchKernelGGL(weights_k, dim3(TT), dim3(512), 0, stream, W1, al1, ar1, W2, al2, ar2, res_w, ws);
    hipLaunchKernelGGL(sort_p1, dim3((EE + P1_CHUNK - 1) / P1_CHUNK), dim3(256), 0, stream, src, dst, etype, wsi);
    hipLaunchKernelGGL(sort_p2, dim3(NBUCK), dim3(256), 0, stream, wsi);
    hipLaunchKernelGGL(gemm_f, dim3((NN + 63) / 64), dim3(512), 0, stream, x, ws + OFF_CW1, ws);
    hipLaunchKernelGGL(agg1, dim3(NN / 4), dim3(256), 0, stream, wsi, ws);
    hipLaunchKernelGGL(gemm_f2, dim3((NN + 63) / 64), dim3(256), 0, stream, ws + OFF_CW2, ws);
    hipLaunchKernelGGL(agg2, dim3(NN / 4), dim3(256), 0, stream, wsi, ws);
    hipLaunchKernelGGL(final_k, dim3(1), dim3(64), 0, stream, res_b, ws, out);
}